// Round 2
// baseline (1439.729 us; speedup 1.0000x reference)
//
#include <hip/hip_runtime.h>

// LSTM_26912265077001: 2-layer LSTM (H=51, IN=1), T=512, B=1024, fp32.
// Persistent kernel, one block per NB=2 batch elements (512 blocks, 2/CU).
// R2 change: weights as macro-generated NAMED SCALARS (w1_k_x ...) so the
// compiler cannot demote them to scratch (R1 had VGPR_Count=104 < 156 weight
// floats -> weights were re-read from memory every step; ~1 ms of L2 traffic).

#define Hs   51
#define HP   52          // padded hidden (pad element always 0)
#define G4   204         // 4*H gate rows
#define Ts   512
#define Bs   1024
#define NB   2
#define NT   256

__device__ __forceinline__ float sig_(float x) {
    return 1.0f / (1.0f + __expf(-x));
}
__device__ __forceinline__ float tanh_(float x) {
    float e = __expf(2.0f * x);
    return 1.0f - 2.0f / (e + 1.0f);
}

#define REP13(M) M(0) M(1) M(2) M(3) M(4) M(5) M(6) M(7) M(8) M(9) M(10) M(11) M(12)

// --- named weight registers: w1 = W_hh1 row, w2 = W_ih2 row, w3 = W_hh2 row ---
#define DW(k) \
    float w1_##k##_x=0.f, w1_##k##_y=0.f, w1_##k##_z=0.f, w1_##k##_w=0.f; \
    float w2_##k##_x=0.f, w2_##k##_y=0.f, w2_##k##_z=0.f, w2_##k##_w=0.f; \
    float w3_##k##_x=0.f, w3_##k##_y=0.f, w3_##k##_z=0.f, w3_##k##_w=0.f;

#define LW(k) \
    w1_##k##_x = W_hh1[r + 4*k + 0]; \
    w1_##k##_y = W_hh1[r + 4*k + 1]; \
    w1_##k##_z = W_hh1[r + 4*k + 2]; \
    w1_##k##_w = (4*k + 3 < Hs) ? W_hh1[r + 4*k + 3] : 0.f; \
    w2_##k##_x = W_ih2[r + 4*k + 0]; \
    w2_##k##_y = W_ih2[r + 4*k + 1]; \
    w2_##k##_z = W_ih2[r + 4*k + 2]; \
    w2_##k##_w = (4*k + 3 < Hs) ? W_ih2[r + 4*k + 3] : 0.f; \
    w3_##k##_x = W_hh2[r + 4*k + 0]; \
    w3_##k##_y = W_hh2[r + 4*k + 1]; \
    w3_##k##_z = W_hh2[r + 4*k + 2]; \
    w3_##k##_w = (4*k + 3 < Hs) ? W_hh2[r + 4*k + 3] : 0.f;

// Phase A: gates1 += W_hh1 . h1   (both batches)
#define FA(k) { \
    float4 a = h10[k]; float4 b = h11[k]; \
    acc0 = fmaf(w1_##k##_x, a.x, acc0); \
    acc0 = fmaf(w1_##k##_y, a.y, acc0); \
    acc0 = fmaf(w1_##k##_z, a.z, acc0); \
    acc0 = fmaf(w1_##k##_w, a.w, acc0); \
    acc1 = fmaf(w1_##k##_x, b.x, acc1); \
    acc1 = fmaf(w1_##k##_y, b.y, acc1); \
    acc1 = fmaf(w1_##k##_z, b.z, acc1); \
    acc1 = fmaf(w1_##k##_w, b.w, acc1); }

// Phase C: gates2 += W_ih2 . h1 + W_hh2 . h2   (both batches)
#define FC(k) { \
    float4 a0 = h10[k]; float4 a1 = h11[k]; \
    float4 b0 = h20[k]; float4 b1 = h21[k]; \
    acc0 = fmaf(w2_##k##_x, a0.x, acc0); \
    acc0 = fmaf(w2_##k##_y, a0.y, acc0); \
    acc0 = fmaf(w2_##k##_z, a0.z, acc0); \
    acc0 = fmaf(w2_##k##_w, a0.w, acc0); \
    acc0 = fmaf(w3_##k##_x, b0.x, acc0); \
    acc0 = fmaf(w3_##k##_y, b0.y, acc0); \
    acc0 = fmaf(w3_##k##_z, b0.z, acc0); \
    acc0 = fmaf(w3_##k##_w, b0.w, acc0); \
    acc1 = fmaf(w2_##k##_x, a1.x, acc1); \
    acc1 = fmaf(w2_##k##_y, a1.y, acc1); \
    acc1 = fmaf(w2_##k##_z, a1.z, acc1); \
    acc1 = fmaf(w2_##k##_w, a1.w, acc1); \
    acc1 = fmaf(w3_##k##_x, b1.x, acc1); \
    acc1 = fmaf(w3_##k##_y, b1.y, acc1); \
    acc1 = fmaf(w3_##k##_z, b1.z, acc1); \
    acc1 = fmaf(w3_##k##_w, b1.w, acc1); }

__global__ __launch_bounds__(NT, 2) void lstm2_kernel(
    const float* __restrict__ x,      // (T, B, 1)
    const float* __restrict__ W_ih1,  // (204, 1)
    const float* __restrict__ W_hh1,  // (204, 51)
    const float* __restrict__ b_ih1,  // (204,)
    const float* __restrict__ b_hh1,  // (204,)
    const float* __restrict__ W_ih2,  // (204, 51)
    const float* __restrict__ W_hh2,  // (204, 51)
    const float* __restrict__ b_ih2,  // (204,)
    const float* __restrict__ b_hh2,  // (204,)
    const float* __restrict__ W_lin,  // (1, 51)
    const float* __restrict__ b_lin,  // (1,)
    float* __restrict__ out)          // (B, T)
{
    __shared__ float xs[Ts][NB];
    __shared__ float h1s[NB][HP];
    __shared__ float h2s[NB][HP];
    __shared__ float gs[NB][G4];
    __shared__ float wlin_s[HP];
    __shared__ float blin_s;

    const int tid = threadIdx.x;
    const int bg0 = blockIdx.x * NB;

    #pragma unroll
    for (int i = 0; i < (Ts * NB) / NT; ++i) {
        int idx = tid + i * NT;
        int tt  = idx >> 1;
        int b   = idx & 1;
        xs[tt][b] = x[tt * Bs + bg0 + b];
    }
    if (tid < HP) {
        h1s[0][tid] = 0.f; h1s[1][tid] = 0.f;
        h2s[0][tid] = 0.f; h2s[1][tid] = 0.f;
        wlin_s[tid] = (tid < Hs) ? W_lin[tid] : 0.f;
    }
    if (tid == 0) blin_s = b_lin[0];

    REP13(DW)
    float bsum1 = 0.f, bsum2 = 0.f, wih1 = 0.f;
    if (tid < G4) {
        const int r = tid * Hs;
        REP13(LW)
        bsum1 = b_ih1[tid] + b_hh1[tid];
        bsum2 = b_ih2[tid] + b_hh2[tid];
        wih1  = W_ih1[tid];
    }

    const float4* h10 = (const float4*)(&h1s[0][0]);
    const float4* h11 = (const float4*)(&h1s[1][0]);
    const float4* h20 = (const float4*)(&h2s[0][0]);
    const float4* h21 = (const float4*)(&h2s[1][0]);

    float c1 = 0.f, c2 = 0.f;
    __syncthreads();

    for (int t = 0; t < Ts; ++t) {
        // ---- Phase A: layer-1 gate matvec || output dot for t-1 ----
        if (tid < G4) {
            float acc0 = fmaf(wih1, xs[t][0], bsum1);
            float acc1 = fmaf(wih1, xs[t][1], bsum1);
            REP13(FA)
            gs[0][tid] = acc0;
            gs[1][tid] = acc1;
        } else if (t > 0 && tid < G4 + NB) {
            int b = tid - G4;
            const float4* h4 = (b == 0) ? h20 : h21;
            const float4* w4 = (const float4*)(&wlin_s[0]);
            float s = blin_s;
            #pragma unroll
            for (int k4 = 0; k4 < HP / 4; ++k4) {
                float4 a = h4[k4];
                float4 w = w4[k4];
                s += a.x * w.x + a.y * w.y + a.z * w.z + a.w * w.w;
            }
            out[(bg0 + b) * Ts + (t - 1)] = s;
        }
        __syncthreads();

        // ---- Phase B: layer-1 elementwise update ----
        if (tid < NB * Hs) {
            int b = tid / Hs, j = tid % Hs;
            float gi = gs[b][j];
            float gf = gs[b][Hs + j];
            float gg = gs[b][2 * Hs + j];
            float go = gs[b][3 * Hs + j];
            float iv = sig_(gi);
            float fv = sig_(gf);
            float gv = tanh_(gg);
            float ov = sig_(go);
            c1 = fmaf(fv, c1, iv * gv);
            h1s[b][j] = ov * tanh_(c1);
        }
        __syncthreads();

        // ---- Phase C: layer-2 gate matvec ----
        if (tid < G4) {
            float acc0 = bsum2, acc1 = bsum2;
            REP13(FC)
            gs[0][tid] = acc0;
            gs[1][tid] = acc1;
        }
        __syncthreads();

        // ---- Phase D: layer-2 elementwise update ----
        if (tid < NB * Hs) {
            int b = tid / Hs, j = tid % Hs;
            float gi = gs[b][j];
            float gf = gs[b][Hs + j];
            float gg = gs[b][2 * Hs + j];
            float go = gs[b][3 * Hs + j];
            float iv = sig_(gi);
            float fv = sig_(gf);
            float gv = tanh_(gg);
            float ov = sig_(go);
            c2 = fmaf(fv, c2, iv * gv);
            h2s[b][j] = ov * tanh_(c2);
        }
        __syncthreads();
    }

    if (tid >= G4 && tid < G4 + NB) {
        int b = tid - G4;
        const float4* h4 = (b == 0) ? h20 : h21;
        const float4* w4 = (const float4*)(&wlin_s[0]);
        float s = blin_s;
        #pragma unroll
        for (int k4 = 0; k4 < HP / 4; ++k4) {
            float4 a = h4[k4];
            float4 w = w4[k4];
            s += a.x * w.x + a.y * w.y + a.z * w.z + a.w * w.w;
        }
        out[(bg0 + b) * Ts + (Ts - 1)] = s;
    }
}

extern "C" void kernel_launch(void* const* d_in, const int* in_sizes, int n_in,
                              void* d_out, int out_size, void* d_ws, size_t ws_size,
                              hipStream_t stream) {
    const float* x     = (const float*)d_in[0];
    const float* W_ih1 = (const float*)d_in[1];
    const float* W_hh1 = (const float*)d_in[2];
    const float* b_ih1 = (const float*)d_in[3];
    const float* b_hh1 = (const float*)d_in[4];
    const float* W_ih2 = (const float*)d_in[5];
    const float* W_hh2 = (const float*)d_in[6];
    const float* b_ih2 = (const float*)d_in[7];
    const float* b_hh2 = (const float*)d_in[8];
    const float* W_lin = (const float*)d_in[9];
    const float* b_lin = (const float*)d_in[10];
    float* out = (float*)d_out;

    lstm2_kernel<<<Bs / NB, NT, 0, stream>>>(
        x, W_ih1, W_hh1, b_ih1, b_hh1,
        W_ih2, W_hh2, b_ih2, b_hh2, W_lin, b_lin, out);
}

// Round 3
// 1438.151 us; speedup vs baseline: 1.0011x; 1.0011x over previous
//
#include <hip/hip_runtime.h>

// LSTM_26912265077001: 2-layer LSTM (H=51, IN=1), T=512, B=1024, fp32.
// Persistent kernel, one block per NB=2 batch elements (512 blocks, 2/CU).
// R3 change: pin occupancy with amdgpu_waves_per_eu(2,2). R2 showed
// VGPR_Count=108 (<156 weight floats): with an open waves-per-eu max the
// backend spills weights to scratch to chase 4 waves/SIMD -- occupancy the
// 512-block grid can never use (2 blocks/CU is the max). min=max=2 gives the
// allocator the full 256-VGPR budget so the weight rows stay resident.

#define Hs   51
#define HP   52          // padded hidden (pad element always 0)
#define G4   204         // 4*H gate rows
#define Ts   512
#define Bs   1024
#define NB   2
#define NT   256

__device__ __forceinline__ float sig_(float x) {
    return 1.0f / (1.0f + __expf(-x));
}
__device__ __forceinline__ float tanh_(float x) {
    float e = __expf(2.0f * x);
    return 1.0f - 2.0f / (e + 1.0f);
}

#define REP13(M) M(0) M(1) M(2) M(3) M(4) M(5) M(6) M(7) M(8) M(9) M(10) M(11) M(12)

// --- named weight registers: w1 = W_hh1 row, w2 = W_ih2 row, w3 = W_hh2 row ---
#define DW(k) \
    float w1_##k##_x=0.f, w1_##k##_y=0.f, w1_##k##_z=0.f, w1_##k##_w=0.f; \
    float w2_##k##_x=0.f, w2_##k##_y=0.f, w2_##k##_z=0.f, w2_##k##_w=0.f; \
    float w3_##k##_x=0.f, w3_##k##_y=0.f, w3_##k##_z=0.f, w3_##k##_w=0.f;

#define LW(k) \
    w1_##k##_x = W_hh1[r + 4*k + 0]; \
    w1_##k##_y = W_hh1[r + 4*k + 1]; \
    w1_##k##_z = W_hh1[r + 4*k + 2]; \
    w1_##k##_w = (4*k + 3 < Hs) ? W_hh1[r + 4*k + 3] : 0.f; \
    w2_##k##_x = W_ih2[r + 4*k + 0]; \
    w2_##k##_y = W_ih2[r + 4*k + 1]; \
    w2_##k##_z = W_ih2[r + 4*k + 2]; \
    w2_##k##_w = (4*k + 3 < Hs) ? W_ih2[r + 4*k + 3] : 0.f; \
    w3_##k##_x = W_hh2[r + 4*k + 0]; \
    w3_##k##_y = W_hh2[r + 4*k + 1]; \
    w3_##k##_z = W_hh2[r + 4*k + 2]; \
    w3_##k##_w = (4*k + 3 < Hs) ? W_hh2[r + 4*k + 3] : 0.f;

// Phase A: gates1 += W_hh1 . h1   (both batches)
#define FA(k) { \
    float4 a = h10[k]; float4 b = h11[k]; \
    acc0 = fmaf(w1_##k##_x, a.x, acc0); \
    acc0 = fmaf(w1_##k##_y, a.y, acc0); \
    acc0 = fmaf(w1_##k##_z, a.z, acc0); \
    acc0 = fmaf(w1_##k##_w, a.w, acc0); \
    acc1 = fmaf(w1_##k##_x, b.x, acc1); \
    acc1 = fmaf(w1_##k##_y, b.y, acc1); \
    acc1 = fmaf(w1_##k##_z, b.z, acc1); \
    acc1 = fmaf(w1_##k##_w, b.w, acc1); }

// Phase C: gates2 += W_ih2 . h1 + W_hh2 . h2   (both batches)
#define FC(k) { \
    float4 a0 = h10[k]; float4 a1 = h11[k]; \
    float4 b0 = h20[k]; float4 b1 = h21[k]; \
    acc0 = fmaf(w2_##k##_x, a0.x, acc0); \
    acc0 = fmaf(w2_##k##_y, a0.y, acc0); \
    acc0 = fmaf(w2_##k##_z, a0.z, acc0); \
    acc0 = fmaf(w2_##k##_w, a0.w, acc0); \
    acc0 = fmaf(w3_##k##_x, b0.x, acc0); \
    acc0 = fmaf(w3_##k##_y, b0.y, acc0); \
    acc0 = fmaf(w3_##k##_z, b0.z, acc0); \
    acc0 = fmaf(w3_##k##_w, b0.w, acc0); \
    acc1 = fmaf(w2_##k##_x, a1.x, acc1); \
    acc1 = fmaf(w2_##k##_y, a1.y, acc1); \
    acc1 = fmaf(w2_##k##_z, a1.z, acc1); \
    acc1 = fmaf(w2_##k##_w, a1.w, acc1); \
    acc1 = fmaf(w3_##k##_x, b1.x, acc1); \
    acc1 = fmaf(w3_##k##_y, b1.y, acc1); \
    acc1 = fmaf(w3_##k##_z, b1.z, acc1); \
    acc1 = fmaf(w3_##k##_w, b1.w, acc1); }

__global__ void
__attribute__((amdgpu_flat_work_group_size(NT, NT), amdgpu_waves_per_eu(2, 2)))
lstm2_kernel(
    const float* __restrict__ x,      // (T, B, 1)
    const float* __restrict__ W_ih1,  // (204, 1)
    const float* __restrict__ W_hh1,  // (204, 51)
    const float* __restrict__ b_ih1,  // (204,)
    const float* __restrict__ b_hh1,  // (204,)
    const float* __restrict__ W_ih2,  // (204, 51)
    const float* __restrict__ W_hh2,  // (204, 51)
    const float* __restrict__ b_ih2,  // (204,)
    const float* __restrict__ b_hh2,  // (204,)
    const float* __restrict__ W_lin,  // (1, 51)
    const float* __restrict__ b_lin,  // (1,)
    float* __restrict__ out)          // (B, T)
{
    __shared__ float xs[Ts][NB];
    __shared__ float h1s[NB][HP];
    __shared__ float h2s[NB][HP];
    __shared__ float gs[NB][G4];
    __shared__ float wlin_s[HP];
    __shared__ float blin_s;

    const int tid = threadIdx.x;
    const int bg0 = blockIdx.x * NB;

    #pragma unroll
    for (int i = 0; i < (Ts * NB) / NT; ++i) {
        int idx = tid + i * NT;
        int tt  = idx >> 1;
        int b   = idx & 1;
        xs[tt][b] = x[tt * Bs + bg0 + b];
    }
    if (tid < HP) {
        h1s[0][tid] = 0.f; h1s[1][tid] = 0.f;
        h2s[0][tid] = 0.f; h2s[1][tid] = 0.f;
        wlin_s[tid] = (tid < Hs) ? W_lin[tid] : 0.f;
    }
    if (tid == 0) blin_s = b_lin[0];

    REP13(DW)
    float bsum1 = 0.f, bsum2 = 0.f, wih1 = 0.f;
    if (tid < G4) {
        const int r = tid * Hs;
        REP13(LW)
        bsum1 = b_ih1[tid] + b_hh1[tid];
        bsum2 = b_ih2[tid] + b_hh2[tid];
        wih1  = W_ih1[tid];
    }

    const float4* h10 = (const float4*)(&h1s[0][0]);
    const float4* h11 = (const float4*)(&h1s[1][0]);
    const float4* h20 = (const float4*)(&h2s[0][0]);
    const float4* h21 = (const float4*)(&h2s[1][0]);

    float c1 = 0.f, c2 = 0.f;
    __syncthreads();

    for (int t = 0; t < Ts; ++t) {
        // ---- Phase A: layer-1 gate matvec || output dot for t-1 ----
        if (tid < G4) {
            float acc0 = fmaf(wih1, xs[t][0], bsum1);
            float acc1 = fmaf(wih1, xs[t][1], bsum1);
            REP13(FA)
            gs[0][tid] = acc0;
            gs[1][tid] = acc1;
        } else if (t > 0 && tid < G4 + NB) {
            int b = tid - G4;
            const float4* h4 = (b == 0) ? h20 : h21;
            const float4* w4 = (const float4*)(&wlin_s[0]);
            float s = blin_s;
            #pragma unroll
            for (int k4 = 0; k4 < HP / 4; ++k4) {
                float4 a = h4[k4];
                float4 w = w4[k4];
                s += a.x * w.x + a.y * w.y + a.z * w.z + a.w * w.w;
            }
            out[(bg0 + b) * Ts + (t - 1)] = s;
        }
        __syncthreads();

        // ---- Phase B: layer-1 elementwise update ----
        if (tid < NB * Hs) {
            int b = tid / Hs, j = tid % Hs;
            float gi = gs[b][j];
            float gf = gs[b][Hs + j];
            float gg = gs[b][2 * Hs + j];
            float go = gs[b][3 * Hs + j];
            float iv = sig_(gi);
            float fv = sig_(gf);
            float gv = tanh_(gg);
            float ov = sig_(go);
            c1 = fmaf(fv, c1, iv * gv);
            h1s[b][j] = ov * tanh_(c1);
        }
        __syncthreads();

        // ---- Phase C: layer-2 gate matvec ----
        if (tid < G4) {
            float acc0 = bsum2, acc1 = bsum2;
            REP13(FC)
            gs[0][tid] = acc0;
            gs[1][tid] = acc1;
        }
        __syncthreads();

        // ---- Phase D: layer-2 elementwise update ----
        if (tid < NB * Hs) {
            int b = tid / Hs, j = tid % Hs;
            float gi = gs[b][j];
            float gf = gs[b][Hs + j];
            float gg = gs[b][2 * Hs + j];
            float go = gs[b][3 * Hs + j];
            float iv = sig_(gi);
            float fv = sig_(gf);
            float gv = tanh_(gg);
            float ov = sig_(go);
            c2 = fmaf(fv, c2, iv * gv);
            h2s[b][j] = ov * tanh_(c2);
        }
        __syncthreads();
    }

    if (tid >= G4 && tid < G4 + NB) {
        int b = tid - G4;
        const float4* h4 = (b == 0) ? h20 : h21;
        const float4* w4 = (const float4*)(&wlin_s[0]);
        float s = blin_s;
        #pragma unroll
        for (int k4 = 0; k4 < HP / 4; ++k4) {
            float4 a = h4[k4];
            float4 w = w4[k4];
            s += a.x * w.x + a.y * w.y + a.z * w.z + a.w * w.w;
        }
        out[(bg0 + b) * Ts + (Ts - 1)] = s;
    }
}

extern "C" void kernel_launch(void* const* d_in, const int* in_sizes, int n_in,
                              void* d_out, int out_size, void* d_ws, size_t ws_size,
                              hipStream_t stream) {
    const float* x     = (const float*)d_in[0];
    const float* W_ih1 = (const float*)d_in[1];
    const float* W_hh1 = (const float*)d_in[2];
    const float* b_ih1 = (const float*)d_in[3];
    const float* b_hh1 = (const float*)d_in[4];
    const float* W_ih2 = (const float*)d_in[5];
    const float* W_hh2 = (const float*)d_in[6];
    const float* b_ih2 = (const float*)d_in[7];
    const float* b_hh2 = (const float*)d_in[8];
    const float* W_lin = (const float*)d_in[9];
    const float* b_lin = (const float*)d_in[10];
    float* out = (float*)d_out;

    lstm2_kernel<<<Bs / NB, NT, 0, stream>>>(
        x, W_ih1, W_hh1, b_ih1, b_hh1,
        W_ih2, W_hh2, b_ih2, b_hh2, W_lin, b_lin, out);
}

// Round 4
// 1432.085 us; speedup vs baseline: 1.0053x; 1.0042x over previous
//
#include <hip/hip_runtime.h>

// LSTM_26912265077001: 2-layer LSTM (H=51, IN=1), T=512, B=1024, fp32.
// Persistent kernel, one block per NB=2 batch elements (512 blocks, 2/CU).
// R4 change: asm-volatile pin of each weight after its load. R2/R3 showed
// VGPR_Count=108 regardless of occupancy attributes: LLVM sinks the
// (restrict, invariant) weight loads into the t-loop, re-reading 125 KB/block
// /step through L2 (~32 GB total ~ 1 ms). A volatile empty asm with "+v"
// cannot be sunk into the loop, forcing the 153 weight floats to stay
// register-resident; waves_per_eu(2,2) provides the 256-VGPR budget.

#define Hs   51
#define HP   52          // padded hidden (pad element always 0)
#define G4   204         // 4*H gate rows
#define Ts   512
#define Bs   1024
#define NB   2
#define NT   256

__device__ __forceinline__ float sig_(float x) {
    return 1.0f / (1.0f + __expf(-x));
}
__device__ __forceinline__ float tanh_(float x) {
    float e = __expf(2.0f * x);
    return 1.0f - 2.0f / (e + 1.0f);
}

#define REP13(M) M(0) M(1) M(2) M(3) M(4) M(5) M(6) M(7) M(8) M(9) M(10) M(11) M(12)

// --- named weight registers: w1 = W_hh1 row, w2 = W_ih2 row, w3 = W_hh2 row ---
#define DW(k) \
    float w1_##k##_x=0.f, w1_##k##_y=0.f, w1_##k##_z=0.f, w1_##k##_w=0.f; \
    float w2_##k##_x=0.f, w2_##k##_y=0.f, w2_##k##_z=0.f, w2_##k##_w=0.f; \
    float w3_##k##_x=0.f, w3_##k##_y=0.f, w3_##k##_z=0.f, w3_##k##_w=0.f;

#define LW(k) \
    w1_##k##_x = W_hh1[r + 4*k + 0]; \
    w1_##k##_y = W_hh1[r + 4*k + 1]; \
    w1_##k##_z = W_hh1[r + 4*k + 2]; \
    w1_##k##_w = (4*k + 3 < Hs) ? W_hh1[r + 4*k + 3] : 0.f; \
    w2_##k##_x = W_ih2[r + 4*k + 0]; \
    w2_##k##_y = W_ih2[r + 4*k + 1]; \
    w2_##k##_z = W_ih2[r + 4*k + 2]; \
    w2_##k##_w = (4*k + 3 < Hs) ? W_ih2[r + 4*k + 3] : 0.f; \
    w3_##k##_x = W_hh2[r + 4*k + 0]; \
    w3_##k##_y = W_hh2[r + 4*k + 1]; \
    w3_##k##_z = W_hh2[r + 4*k + 2]; \
    w3_##k##_w = (4*k + 3 < Hs) ? W_hh2[r + 4*k + 3] : 0.f;

// Pin loaded weights in VGPRs: volatile asm cannot be sunk into the loop,
// so the values become non-rematerializable and must stay live.
#define PIN(k) \
    asm volatile("" : "+v"(w1_##k##_x), "+v"(w1_##k##_y), "+v"(w1_##k##_z), "+v"(w1_##k##_w)); \
    asm volatile("" : "+v"(w2_##k##_x), "+v"(w2_##k##_y), "+v"(w2_##k##_z), "+v"(w2_##k##_w)); \
    asm volatile("" : "+v"(w3_##k##_x), "+v"(w3_##k##_y), "+v"(w3_##k##_z), "+v"(w3_##k##_w));

// Phase A: gates1 += W_hh1 . h1   (both batches)
#define FA(k) { \
    float4 a = h10[k]; float4 b = h11[k]; \
    acc0 = fmaf(w1_##k##_x, a.x, acc0); \
    acc0 = fmaf(w1_##k##_y, a.y, acc0); \
    acc0 = fmaf(w1_##k##_z, a.z, acc0); \
    acc0 = fmaf(w1_##k##_w, a.w, acc0); \
    acc1 = fmaf(w1_##k##_x, b.x, acc1); \
    acc1 = fmaf(w1_##k##_y, b.y, acc1); \
    acc1 = fmaf(w1_##k##_z, b.z, acc1); \
    acc1 = fmaf(w1_##k##_w, b.w, acc1); }

// Phase C: gates2 += W_ih2 . h1 + W_hh2 . h2   (both batches)
#define FC(k) { \
    float4 a0 = h10[k]; float4 a1 = h11[k]; \
    float4 b0 = h20[k]; float4 b1 = h21[k]; \
    acc0 = fmaf(w2_##k##_x, a0.x, acc0); \
    acc0 = fmaf(w2_##k##_y, a0.y, acc0); \
    acc0 = fmaf(w2_##k##_z, a0.z, acc0); \
    acc0 = fmaf(w2_##k##_w, a0.w, acc0); \
    acc0 = fmaf(w3_##k##_x, b0.x, acc0); \
    acc0 = fmaf(w3_##k##_y, b0.y, acc0); \
    acc0 = fmaf(w3_##k##_z, b0.z, acc0); \
    acc0 = fmaf(w3_##k##_w, b0.w, acc0); \
    acc1 = fmaf(w2_##k##_x, a1.x, acc1); \
    acc1 = fmaf(w2_##k##_y, a1.y, acc1); \
    acc1 = fmaf(w2_##k##_z, a1.z, acc1); \
    acc1 = fmaf(w2_##k##_w, a1.w, acc1); \
    acc1 = fmaf(w3_##k##_x, b1.x, acc1); \
    acc1 = fmaf(w3_##k##_y, b1.y, acc1); \
    acc1 = fmaf(w3_##k##_z, b1.z, acc1); \
    acc1 = fmaf(w3_##k##_w, b1.w, acc1); }

__global__ void
__attribute__((amdgpu_flat_work_group_size(NT, NT), amdgpu_waves_per_eu(2, 2)))
lstm2_kernel(
    const float* __restrict__ x,      // (T, B, 1)
    const float* __restrict__ W_ih1,  // (204, 1)
    const float* __restrict__ W_hh1,  // (204, 51)
    const float* __restrict__ b_ih1,  // (204,)
    const float* __restrict__ b_hh1,  // (204,)
    const float* __restrict__ W_ih2,  // (204, 51)
    const float* __restrict__ W_hh2,  // (204, 51)
    const float* __restrict__ b_ih2,  // (204,)
    const float* __restrict__ b_hh2,  // (204,)
    const float* __restrict__ W_lin,  // (1, 51)
    const float* __restrict__ b_lin,  // (1,)
    float* __restrict__ out)          // (B, T)
{
    __shared__ float xs[Ts][NB];
    __shared__ float h1s[NB][HP];
    __shared__ float h2s[NB][HP];
    __shared__ float gs[NB][G4];
    __shared__ float wlin_s[HP];
    __shared__ float blin_s;

    const int tid = threadIdx.x;
    const int bg0 = blockIdx.x * NB;

    #pragma unroll
    for (int i = 0; i < (Ts * NB) / NT; ++i) {
        int idx = tid + i * NT;
        int tt  = idx >> 1;
        int b   = idx & 1;
        xs[tt][b] = x[tt * Bs + bg0 + b];
    }
    if (tid < HP) {
        h1s[0][tid] = 0.f; h1s[1][tid] = 0.f;
        h2s[0][tid] = 0.f; h2s[1][tid] = 0.f;
        wlin_s[tid] = (tid < Hs) ? W_lin[tid] : 0.f;
    }
    if (tid == 0) blin_s = b_lin[0];

    REP13(DW)
    float bsum1 = 0.f, bsum2 = 0.f, wih1 = 0.f;
    if (tid < G4) {
        const int r = tid * Hs;
        REP13(LW)
        REP13(PIN)
        bsum1 = b_ih1[tid] + b_hh1[tid];
        bsum2 = b_ih2[tid] + b_hh2[tid];
        wih1  = W_ih1[tid];
        asm volatile("" : "+v"(bsum1), "+v"(bsum2), "+v"(wih1));
    }

    const float4* h10 = (const float4*)(&h1s[0][0]);
    const float4* h11 = (const float4*)(&h1s[1][0]);
    const float4* h20 = (const float4*)(&h2s[0][0]);
    const float4* h21 = (const float4*)(&h2s[1][0]);

    float c1 = 0.f, c2 = 0.f;
    __syncthreads();

    for (int t = 0; t < Ts; ++t) {
        // ---- Phase A: layer-1 gate matvec || output dot for t-1 ----
        if (tid < G4) {
            float acc0 = fmaf(wih1, xs[t][0], bsum1);
            float acc1 = fmaf(wih1, xs[t][1], bsum1);
            REP13(FA)
            gs[0][tid] = acc0;
            gs[1][tid] = acc1;
        } else if (t > 0 && tid < G4 + NB) {
            int b = tid - G4;
            const float4* h4 = (b == 0) ? h20 : h21;
            const float4* w4 = (const float4*)(&wlin_s[0]);
            float s = blin_s;
            #pragma unroll
            for (int k4 = 0; k4 < HP / 4; ++k4) {
                float4 a = h4[k4];
                float4 w = w4[k4];
                s += a.x * w.x + a.y * w.y + a.z * w.z + a.w * w.w;
            }
            out[(bg0 + b) * Ts + (t - 1)] = s;
        }
        __syncthreads();

        // ---- Phase B: layer-1 elementwise update ----
        if (tid < NB * Hs) {
            int b = tid / Hs, j = tid % Hs;
            float gi = gs[b][j];
            float gf = gs[b][Hs + j];
            float gg = gs[b][2 * Hs + j];
            float go = gs[b][3 * Hs + j];
            float iv = sig_(gi);
            float fv = sig_(gf);
            float gv = tanh_(gg);
            float ov = sig_(go);
            c1 = fmaf(fv, c1, iv * gv);
            h1s[b][j] = ov * tanh_(c1);
        }
        __syncthreads();

        // ---- Phase C: layer-2 gate matvec ----
        if (tid < G4) {
            float acc0 = bsum2, acc1 = bsum2;
            REP13(FC)
            gs[0][tid] = acc0;
            gs[1][tid] = acc1;
        }
        __syncthreads();

        // ---- Phase D: layer-2 elementwise update ----
        if (tid < NB * Hs) {
            int b = tid / Hs, j = tid % Hs;
            float gi = gs[b][j];
            float gf = gs[b][Hs + j];
            float gg = gs[b][2 * Hs + j];
            float go = gs[b][3 * Hs + j];
            float iv = sig_(gi);
            float fv = sig_(gf);
            float gv = tanh_(gg);
            float ov = sig_(go);
            c2 = fmaf(fv, c2, iv * gv);
            h2s[b][j] = ov * tanh_(c2);
        }
        __syncthreads();
    }

    if (tid >= G4 && tid < G4 + NB) {
        int b = tid - G4;
        const float4* h4 = (b == 0) ? h20 : h21;
        const float4* w4 = (const float4*)(&wlin_s[0]);
        float s = blin_s;
        #pragma unroll
        for (int k4 = 0; k4 < HP / 4; ++k4) {
            float4 a = h4[k4];
            float4 w = w4[k4];
            s += a.x * w.x + a.y * w.y + a.z * w.z + a.w * w.w;
        }
        out[(bg0 + b) * Ts + (Ts - 1)] = s;
    }
}

extern "C" void kernel_launch(void* const* d_in, const int* in_sizes, int n_in,
                              void* d_out, int out_size, void* d_ws, size_t ws_size,
                              hipStream_t stream) {
    const float* x     = (const float*)d_in[0];
    const float* W_ih1 = (const float*)d_in[1];
    const float* W_hh1 = (const float*)d_in[2];
    const float* b_ih1 = (const float*)d_in[3];
    const float* b_hh1 = (const float*)d_in[4];
    const float* W_ih2 = (const float*)d_in[5];
    const float* W_hh2 = (const float*)d_in[6];
    const float* b_ih2 = (const float*)d_in[7];
    const float* b_hh2 = (const float*)d_in[8];
    const float* W_lin = (const float*)d_in[9];
    const float* b_lin = (const float*)d_in[10];
    float* out = (float*)d_out;

    lstm2_kernel<<<Bs / NB, NT, 0, stream>>>(
        x, W_ih1, W_hh1, b_ih1, b_hh1,
        W_ih2, W_hh2, b_ih2, b_hh2, W_lin, b_lin, out);
}